// Round 6
// baseline (430.342 us; speedup 1.0000x reference)
//
#include <hip/hip_runtime.h>

__device__ __forceinline__ float2 cmul(float2 a, float2 b) {
    return make_float2(a.x*b.x - a.y*b.y, a.x*b.y + a.y*b.x);
}
__device__ __forceinline__ float2 cadd(float2 a, float2 b){ return make_float2(a.x+b.x, a.y+b.y); }
__device__ __forceinline__ float2 csub(float2 a, float2 b){ return make_float2(a.x-b.x, a.y-b.y); }

// Native clang vector for nontemporal 16B stores (__builtin_nontemporal_store
// rejects HIP_vector_type float4 -- it wants a true vector of float).
typedef float nt4 __attribute__((ext_vector_type(4)));
__device__ __forceinline__ void nt_store16(float ax, float ay, float bx, float by,
                                           void* p) {
    nt4 t; t.x = ax; t.y = ay; t.z = bx; t.w = by;
    __builtin_nontemporal_store(t, (nt4*)p);
}

// Wave-local LDS "barrier": all lane-exchange in the FFTs is within ONE wave
// (scratch regions are per-wave disjoint), so no s_barrier is needed.
__device__ __forceinline__ void wsync() {
    asm volatile("s_waitcnt lgkmcnt(0)" ::: "memory");
}

// multiply by (0, SGN): forward SGN=-1, inverse SGN=+1
template<int SGN> __device__ __forceinline__ float2 mul_i(float2 a) {
    return (SGN > 0) ? make_float2(-a.y, a.x) : make_float2(a.y, -a.x);
}
// W8^1 = (r, SGN*r), r = sqrt(0.5)
template<int SGN> __device__ __forceinline__ float2 mul_w81(float2 a) {
    const float r = 0.70710678118654752440f;
    return (SGN > 0) ? make_float2(r*(a.x - a.y), r*(a.x + a.y))
                     : make_float2(r*(a.x + a.y), r*(a.y - a.x));
}
// W8^3 = (-r, SGN*r)
template<int SGN> __device__ __forceinline__ float2 mul_w83(float2 a) {
    const float r = 0.70710678118654752440f;
    return (SGN > 0) ? make_float2(-r*(a.x + a.y), r*(a.x - a.y))
                     : make_float2(r*(a.y - a.x), -r*(a.x + a.y));
}

// 8-point DFT in registers, natural-order output: out[q] = sum_k in[k] W8^{SGN*qk}
template<int SGN>
__device__ __forceinline__ void bfly8(float2 v[8]) {
    float2 s0 = cadd(v[0], v[4]), d0 = csub(v[0], v[4]);
    float2 s1 = cadd(v[1], v[5]), d1 = csub(v[1], v[5]);
    float2 s2 = cadd(v[2], v[6]), d2 = csub(v[2], v[6]);
    float2 s3 = cadd(v[3], v[7]), d3 = csub(v[3], v[7]);
    d1 = mul_w81<SGN>(d1);
    d2 = mul_i<SGN>(d2);
    d3 = mul_w83<SGN>(d3);
    float2 p0 = cadd(s0, s2), q0 = csub(s0, s2);
    float2 p1 = cadd(s1, s3), q1 = mul_i<SGN>(csub(s1, s3));
    float2 P0 = cadd(d0, d2), Q0 = csub(d0, d2);
    float2 P1 = cadd(d1, d3), Q1 = mul_i<SGN>(csub(d1, d3));
    v[0] = cadd(p0, p1);
    v[4] = csub(p0, p1);
    v[2] = cadd(q0, q1);
    v[6] = csub(q0, q1);
    v[1] = cadd(P0, P1);
    v[5] = csub(P0, P1);
    v[3] = cadd(Q0, Q1);
    v[7] = csub(Q0, Q1);
}

// v[q] *= W^{SGN*q}, W = cis(2*pi*frac)
template<int SGN>
__device__ __forceinline__ void twiddle7(float2 v[8], float frac) {
    const float ang = (SGN > 0 ? 6.2831853071795864769f : -6.2831853071795864769f) * frac;
    float sn, cs; __sincosf(ang, &sn, &cs);
    const float2 w1 = make_float2(cs, sn);
    float2 w = w1;
    v[1] = cmul(v[1], w);
#pragma unroll
    for (int q = 2; q < 8; ++q) { w = cmul(w, w1); v[q] = cmul(v[q], w); }
}

// Swizzles for the two LDS exchanges (both uniform 4 accesses/bank for b64):
//   f1(a) = a + 2*(a>>6)  (exchange stride-64 <-> stride-8 pattern)
//   f2(a) = a + (a>>3)    (exchange stride-8  <-> contiguous pattern)

// Forward 512-pt FFT, one wave, lane l (0..63), v preloaded with h = l+64k.
// Output: v[q] = spectrum value at position p = 8l+q (freq = octal-digit-rev(p)).
// S: per-wave scratch, >= 575 float2. Wave-local sync only -- no block barriers.
__device__ __forceinline__ void fft512_fwd(float2 v[8], float2* S, int l) {
    const int g = l >> 3, j = l & 7;
    bfly8<-1>(v);
    twiddle7<-1>(v, (float)l * (1.0f/512.0f));
#pragma unroll
    for (int q = 0; q < 8; ++q) S[66*q + l] = v[q];          // f1(64q+l)
    wsync();
#pragma unroll
    for (int k = 0; k < 8; ++k) v[k] = S[66*g + j + 8*k];    // f1(64g+j+8k)
    bfly8<-1>(v);
    twiddle7<-1>(v, (float)j * (1.0f/64.0f));
#pragma unroll
    for (int q = 0; q < 8; ++q) S[72*g + 9*q + j] = v[q];    // f2(64g+8q+j)
    wsync();
#pragma unroll
    for (int k = 0; k < 8; ++k) v[k] = S[9*l + k];           // f2(8l+k)
    bfly8<-1>(v);
}

// Inverse (unscaled, x512): input v[q] = value at position 8l+q, output
// v[k] = natural-order sample at h = l+64k. Exact mirror of fft512_fwd.
__device__ __forceinline__ void fft512_inv(float2 v[8], float2* S, int l) {
    const int g = l >> 3, j = l & 7;
    bfly8<1>(v);
#pragma unroll
    for (int k = 0; k < 8; ++k) S[9*l + k] = v[k];
    wsync();
#pragma unroll
    for (int q = 0; q < 8; ++q) v[q] = S[72*g + 9*q + j];
    twiddle7<1>(v, (float)j * (1.0f/64.0f));
    bfly8<1>(v);
#pragma unroll
    for (int k = 0; k < 8; ++k) S[66*g + j + 8*k] = v[k];
    wsync();
#pragma unroll
    for (int q = 0; q < 8; ++q) v[q] = S[66*q + l];
    twiddle7<1>(v, (float)l * (1.0f/512.0f));
    bfly8<1>(v);
}

__device__ __forceinline__ int drev(int x) {   // reverse 3 octal digits of 9-bit x
    return ((x & 7) << 6) | (x & 56) | (x >> 6);
}

// Fused prologue + pass 1.
// Blocks 0..511: Hp[pw*512 + ph] = Hh[drev(ph)][drev(pw)], Hh = Hermitian
// part of the filter (for real x, Re(ifft2(fft2(x)*H)) == ifft2(fft2(x)*Hh),
// a real linear map, so two planes pack as re/im of one complex plane).
// Blocks 512..8703: forward FFT along W, one row per wave, 4 waves/block.
// Bulk ws writes are NONTEMPORAL: each ws byte is written once and read once
// (by the next kernel), so L2 write-allocate is pure overhead; nt streams
// the store past the dirty-line lifecycle (theory: lifts the measured
// 1.6 TB/s write wall toward the ~3.15 TB/s copy-write ceiling).
__global__ __launch_bounds__(256) void pass1_rows(const float* __restrict__ x,
                                                  float2* __restrict__ ws,
                                                  const float* __restrict__ Hr,
                                                  const float* __restrict__ Hi,
                                                  float2* __restrict__ Hp) {
    if (blockIdx.x < 512) {            // permH half
        const int pw = blockIdx.x;
        const int kw = drev(pw);
        const int nw = (512 - kw) & 511;
        for (int ph = threadIdx.x; ph < 512; ph += 256) {
            const int kh = drev(ph);
            const int nh = (512 - kh) & 511;
            const float hr = 0.5f * (Hr[(kh << 9) + kw] + Hr[(nh << 9) + nw]);
            const float hi = 0.5f * (Hi[(kh << 9) + kw] - Hi[(nh << 9) + nw]);
            Hp[(pw << 9) + ph] = make_float2(hr, hi);
        }
        return;
    }
    __shared__ float2 smem[4 * 577];
    const int t = threadIdx.x;
    const int l = t & 63, w = t >> 6;
    float2* S = smem + w * 577;
    const size_t row = (size_t)(blockIdx.x - 512) * 4 + w;  // 0..32767
    const size_t img = row >> 9;                     // 0..63
    const size_t h   = row & 511;
    const float* src1 = x + ((img * 2) << 18) + (h << 9);
    const float* src2 = src1 + (1 << 18);
    float2 v[8];
#pragma unroll
    for (int k = 0; k < 8; ++k) v[k] = make_float2(src1[l + 64*k], src2[l + 64*k]);
    fft512_fwd(v, S, l);
    float2* dst = ws + row * 512 + 8*l;              // 64B contiguous per lane
#pragma unroll
    for (int q = 0; q < 4; ++q)
        nt_store16(v[2*q].x, v[2*q].y, v[2*q+1].x, v[2*q+1].y, dst + 2*q);
}

// Pass 2: 8 adjacent columns per block (512 thr = 8 waves), one column per
// wave. Coop line-complete staging (float4, 16B/lane); FFT scratch aliases
// the staging buffer. Stage-out is nontemporal.
__global__ __launch_bounds__(512) void pass2_cols(float2* __restrict__ ws,
                                                  const float2* __restrict__ Hp) {
    __shared__ float2 smem[4616];      // interleaved staging 9*511+7 <= 4606; 8 scratches of 577
    const int t = threadIdx.x;
    const int l = t & 63, w = t >> 6;  // wave id == column-in-tile
    const int img = blockIdx.x >> 6;   // 0..63 packed planes
    const int w0 = (blockIdx.x & 63) * 8;
    float2* base = ws + ((size_t)img << 18) + w0;

    {   // stage-in: float4 per lane (2 adjacent columns), line-complete
        const int c = t & 3, u = t >> 2;       // c: column pair, u: 0..127
#pragma unroll
        for (int k = 0; k < 4; ++k) {
            int h = u + 128*k;
            float4 p = *(const float4*)(base + (size_t)h * 512 + 2*c);
            smem[9*h + 2*c]     = make_float2(p.x, p.y);
            smem[9*h + 2*c + 1] = make_float2(p.z, p.w);
        }
    }
    __syncthreads();
    float2 v[8];
#pragma unroll
    for (int k = 0; k < 8; ++k) v[k] = smem[9*(l + 64*k) + w];
    __syncthreads();                   // staging dead; scratch may alias it
    float2* S = smem + w * 577;
    fft512_fwd(v, S, l);
    {   // filter: kh = drev(8l+q), kw = drev(w0+w) — pre-baked into Hp
        const float4* hp = (const float4*)(Hp + (((size_t)(w0 + w)) << 9) + 8*l);
#pragma unroll
        for (int q = 0; q < 4; ++q) {
            float4 h2 = hp[q];
            v[2*q]   = cmul(v[2*q],   make_float2(h2.x, h2.y));
            v[2*q+1] = cmul(v[2*q+1], make_float2(h2.z, h2.w));
        }
    }
    fft512_inv(v, S, l);
    __syncthreads();                   // all waves done with scratch
#pragma unroll
    for (int k = 0; k < 8; ++k) smem[9*(l + 64*k) + w] = v[k];
    __syncthreads();
    {   // stage-out, float4 per lane, line-complete, nontemporal
        const int c = t & 3, u = t >> 2;
#pragma unroll
        for (int k = 0; k < 4; ++k) {
            int h = u + 128*k;
            float2 a = smem[9*h + 2*c], b = smem[9*h + 2*c + 1];
            nt_store16(a.x, a.y, b.x, b.y, base + (size_t)h * 512 + 2*c);
        }
    }
}

// Pass 3: inverse FFT along W, scale 1/512^2; unpack Re -> plane 2m,
// Im -> plane 2m+1. Output stores nontemporal (written once, never re-read).
__global__ __launch_bounds__(256) void pass3_rows(const float2* __restrict__ ws,
                                                  float* __restrict__ out) {
    __shared__ float2 smem[4 * 577];
    const int t = threadIdx.x;
    const int l = t & 63, w = t >> 6;
    float2* S = smem + w * 577;
    const size_t row = (size_t)blockIdx.x * 4 + w;   // 0..32767
    const size_t img = row >> 9;                     // 0..63
    const size_t h   = row & 511;
    const float4* src = (const float4*)(ws + row * 512 + 8*l);
    float2 v[8];
#pragma unroll
    for (int q = 0; q < 4; ++q) {
        float4 p = src[q];
        v[2*q]   = make_float2(p.x, p.y);
        v[2*q+1] = make_float2(p.z, p.w);
    }
    fft512_inv(v, S, l);
    const float sc = 1.0f / (512.0f * 512.0f);
    float* dst1 = out + ((img * 2) << 18) + (h << 9);
    float* dst2 = dst1 + (1 << 18);
#pragma unroll
    for (int k = 0; k < 8; ++k) {
        __builtin_nontemporal_store(v[k].x * sc, dst1 + l + 64*k);
        __builtin_nontemporal_store(v[k].y * sc, dst2 + l + 64*k);
    }
}

extern "C" void kernel_launch(void* const* d_in, const int* in_sizes, int n_in,
                              void* d_out, int out_size, void* d_ws, size_t ws_size,
                              hipStream_t stream) {
    const float* x  = (const float*)d_in[0];   // [8,16,512,512]
    const float* Hr = (const float*)d_in[1];   // [512,512]
    const float* Hi = (const float*)d_in[2];   // [512,512]
    float* out = (float*)d_out;
    float2* ws = (float2*)d_ws;                // 128 MiB complex workspace (64 packed planes)
    float2* Hp = (float2*)d_out;               // 2 MiB of d_out reused as scratch;
                                               // pass 3 fully overwrites d_out after.

    pass1_rows<<<8704, 256, 0, stream>>>(x, ws, Hr, Hi, Hp);  // permH fused in
    pass2_cols<<<4096, 512, 0, stream>>>(ws, Hp);
    pass3_rows<<<8192, 256, 0, stream>>>(ws, out);
}

// Round 7
// 346.701 us; speedup vs baseline: 1.2412x; 1.2412x over previous
//
#include <hip/hip_runtime.h>

__device__ __forceinline__ float2 cmul(float2 a, float2 b) {
    return make_float2(a.x*b.x - a.y*b.y, a.x*b.y + a.y*b.x);
}
__device__ __forceinline__ float2 cadd(float2 a, float2 b){ return make_float2(a.x+b.x, a.y+b.y); }
__device__ __forceinline__ float2 csub(float2 a, float2 b){ return make_float2(a.x-b.x, a.y-b.y); }

// Wave-local LDS "barrier": all lane-exchange in the FFTs is within ONE wave
// (scratch regions are per-wave disjoint), so no s_barrier is needed.
__device__ __forceinline__ void wsync() {
    asm volatile("s_waitcnt lgkmcnt(0)" ::: "memory");
}

// multiply by (0, SGN): forward SGN=-1, inverse SGN=+1
template<int SGN> __device__ __forceinline__ float2 mul_i(float2 a) {
    return (SGN > 0) ? make_float2(-a.y, a.x) : make_float2(a.y, -a.x);
}
// W8^1 = (r, SGN*r), r = sqrt(0.5)
template<int SGN> __device__ __forceinline__ float2 mul_w81(float2 a) {
    const float r = 0.70710678118654752440f;
    return (SGN > 0) ? make_float2(r*(a.x - a.y), r*(a.x + a.y))
                     : make_float2(r*(a.x + a.y), r*(a.y - a.x));
}
// W8^3 = (-r, SGN*r)
template<int SGN> __device__ __forceinline__ float2 mul_w83(float2 a) {
    const float r = 0.70710678118654752440f;
    return (SGN > 0) ? make_float2(-r*(a.x + a.y), r*(a.x - a.y))
                     : make_float2(r*(a.y - a.x), -r*(a.x + a.y));
}

// 8-point DFT in registers, natural-order output: out[q] = sum_k in[k] W8^{SGN*qk}
template<int SGN>
__device__ __forceinline__ void bfly8(float2 v[8]) {
    float2 s0 = cadd(v[0], v[4]), d0 = csub(v[0], v[4]);
    float2 s1 = cadd(v[1], v[5]), d1 = csub(v[1], v[5]);
    float2 s2 = cadd(v[2], v[6]), d2 = csub(v[2], v[6]);
    float2 s3 = cadd(v[3], v[7]), d3 = csub(v[3], v[7]);
    d1 = mul_w81<SGN>(d1);
    d2 = mul_i<SGN>(d2);
    d3 = mul_w83<SGN>(d3);
    float2 p0 = cadd(s0, s2), q0 = csub(s0, s2);
    float2 p1 = cadd(s1, s3), q1 = mul_i<SGN>(csub(s1, s3));
    float2 P0 = cadd(d0, d2), Q0 = csub(d0, d2);
    float2 P1 = cadd(d1, d3), Q1 = mul_i<SGN>(csub(d1, d3));
    v[0] = cadd(p0, p1);
    v[4] = csub(p0, p1);
    v[2] = cadd(q0, q1);
    v[6] = csub(q0, q1);
    v[1] = cadd(P0, P1);
    v[5] = csub(P0, P1);
    v[3] = cadd(Q0, Q1);
    v[7] = csub(Q0, Q1);
}

// v[q] *= W^{SGN*q}, W = cis(2*pi*frac)
template<int SGN>
__device__ __forceinline__ void twiddle7(float2 v[8], float frac) {
    const float ang = (SGN > 0 ? 6.2831853071795864769f : -6.2831853071795864769f) * frac;
    float sn, cs; __sincosf(ang, &sn, &cs);
    const float2 w1 = make_float2(cs, sn);
    float2 w = w1;
    v[1] = cmul(v[1], w);
#pragma unroll
    for (int q = 2; q < 8; ++q) { w = cmul(w, w1); v[q] = cmul(v[q], w); }
}

// Swizzles for the two LDS exchanges (both uniform 4 accesses/bank for b64):
//   f1(a) = a + 2*(a>>6)  (exchange stride-64 <-> stride-8 pattern)
//   f2(a) = a + (a>>3)    (exchange stride-8  <-> contiguous pattern)

// Forward 512-pt FFT, one wave, lane l (0..63), v preloaded with h = l+64k.
// Output: v[q] = spectrum value at position p = 8l+q (freq = octal-digit-rev(p)).
// S: per-wave scratch, >= 575 float2. Wave-local sync only -- no block barriers.
__device__ __forceinline__ void fft512_fwd(float2 v[8], float2* S, int l) {
    const int g = l >> 3, j = l & 7;
    bfly8<-1>(v);
    twiddle7<-1>(v, (float)l * (1.0f/512.0f));
#pragma unroll
    for (int q = 0; q < 8; ++q) S[66*q + l] = v[q];          // f1(64q+l)
    wsync();
#pragma unroll
    for (int k = 0; k < 8; ++k) v[k] = S[66*g + j + 8*k];    // f1(64g+j+8k)
    bfly8<-1>(v);
    twiddle7<-1>(v, (float)j * (1.0f/64.0f));
#pragma unroll
    for (int q = 0; q < 8; ++q) S[72*g + 9*q + j] = v[q];    // f2(64g+8q+j)
    wsync();
#pragma unroll
    for (int k = 0; k < 8; ++k) v[k] = S[9*l + k];           // f2(8l+k)
    bfly8<-1>(v);
}

// Inverse (unscaled, x512): input v[q] = value at position 8l+q, output
// v[k] = natural-order sample at h = l+64k. Exact mirror of fft512_fwd.
__device__ __forceinline__ void fft512_inv(float2 v[8], float2* S, int l) {
    const int g = l >> 3, j = l & 7;
    bfly8<1>(v);
#pragma unroll
    for (int k = 0; k < 8; ++k) S[9*l + k] = v[k];
    wsync();
#pragma unroll
    for (int q = 0; q < 8; ++q) v[q] = S[72*g + 9*q + j];
    twiddle7<1>(v, (float)j * (1.0f/64.0f));
    bfly8<1>(v);
#pragma unroll
    for (int k = 0; k < 8; ++k) S[66*g + j + 8*k] = v[k];
    wsync();
#pragma unroll
    for (int q = 0; q < 8; ++q) v[q] = S[66*q + l];
    twiddle7<1>(v, (float)l * (1.0f/512.0f));
    bfly8<1>(v);
}

__device__ __forceinline__ int drev(int x) {   // reverse 3 octal digits of 9-bit x
    return ((x & 7) << 6) | (x & 56) | (x >> 6);
}

// Fused prologue + pass 1.
// Blocks 0..511: Hp[pw*512 + ph] = Hh[drev(ph)][drev(pw)], Hh = Hermitian
// part of the filter (for real x, Re(ifft2(fft2(x)*H)) == ifft2(fft2(x)*Hh),
// a real linear map, so two planes pack as re/im of one complex plane).
// Blocks 512..4607: forward FFT along W. TWO rows per wave, software-
// pipelined: both rows' loads issue up front (8 KB in flight per wave --
// 2x the memory-level parallelism), FFT of row A runs under row B's load
// latency, store A overlaps FFT B. Theory: per-wave memory concurrency,
// not DRAM bandwidth, is the 3.2 TB/s limiter.
__global__ __launch_bounds__(256) void pass1_rows(const float* __restrict__ x,
                                                  float2* __restrict__ ws,
                                                  const float* __restrict__ Hr,
                                                  const float* __restrict__ Hi,
                                                  float2* __restrict__ Hp) {
    if (blockIdx.x < 512) {            // permH half
        const int pw = blockIdx.x;
        const int kw = drev(pw);
        const int nw = (512 - kw) & 511;
        for (int ph = threadIdx.x; ph < 512; ph += 256) {
            const int kh = drev(ph);
            const int nh = (512 - kh) & 511;
            const float hr = 0.5f * (Hr[(kh << 9) + kw] + Hr[(nh << 9) + nw]);
            const float hi = 0.5f * (Hi[(kh << 9) + kw] - Hi[(nh << 9) + nw]);
            Hp[(pw << 9) + ph] = make_float2(hr, hi);
        }
        return;
    }
    __shared__ float2 smem[4 * 577];
    const int t = threadIdx.x;
    const int l = t & 63, w = t >> 6;
    float2* S = smem + w * 577;
    const size_t rp  = (size_t)(blockIdx.x - 512) * 4 + w;  // row-pair 0..16383
    const size_t img = rp >> 8;                      // packed plane 0..63
    const size_t h0  = (rp & 255) * 2;               // first row of the pair
    const float* s1 = x + ((img * 2) << 18) + (h0 << 9);
    const float* s2 = s1 + (1 << 18);
    float2 va[8], vb[8];
#pragma unroll
    for (int k = 0; k < 8; ++k) va[k] = make_float2(s1[l + 64*k],       s2[l + 64*k]);
#pragma unroll
    for (int k = 0; k < 8; ++k) vb[k] = make_float2(s1[512 + l + 64*k], s2[512 + l + 64*k]);
    const size_t grow = img * 512 + h0;
    fft512_fwd(va, S, l);
    float4* dstA = (float4*)(ws + grow * 512 + 8*l);   // 64B contiguous per lane
#pragma unroll
    for (int q = 0; q < 4; ++q)
        dstA[q] = make_float4(va[2*q].x, va[2*q].y, va[2*q+1].x, va[2*q+1].y);
    fft512_fwd(vb, S, l);
    float4* dstB = (float4*)(ws + (grow + 1) * 512 + 8*l);
#pragma unroll
    for (int q = 0; q < 4; ++q)
        dstB[q] = make_float4(vb[2*q].x, vb[2*q].y, vb[2*q+1].x, vb[2*q+1].y);
}

// Pass 2: 8 adjacent columns per block (512 thr = 8 waves), one column per
// wave. Coop line-complete staging (float4, 16B/lane); FFT scratch aliases
// the staging buffer. Normal (cached) stores -- NT stores proven 1.84x
// write-amplifying on gfx950 (round 6).
__global__ __launch_bounds__(512) void pass2_cols(float2* __restrict__ ws,
                                                  const float2* __restrict__ Hp) {
    __shared__ float2 smem[4616];      // interleaved staging 9*511+7 <= 4606; 8 scratches of 577
    const int t = threadIdx.x;
    const int l = t & 63, w = t >> 6;  // wave id == column-in-tile
    const int img = blockIdx.x >> 6;   // 0..63 packed planes
    const int w0 = (blockIdx.x & 63) * 8;
    float2* base = ws + ((size_t)img << 18) + w0;

    {   // stage-in: float4 per lane (2 adjacent columns), line-complete
        const int c = t & 3, u = t >> 2;       // c: column pair, u: 0..127
#pragma unroll
        for (int k = 0; k < 4; ++k) {
            int h = u + 128*k;
            float4 p = *(const float4*)(base + (size_t)h * 512 + 2*c);
            smem[9*h + 2*c]     = make_float2(p.x, p.y);
            smem[9*h + 2*c + 1] = make_float2(p.z, p.w);
        }
    }
    __syncthreads();
    float2 v[8];
#pragma unroll
    for (int k = 0; k < 8; ++k) v[k] = smem[9*(l + 64*k) + w];
    __syncthreads();                   // staging dead; scratch may alias it
    float2* S = smem + w * 577;
    fft512_fwd(v, S, l);
    {   // filter: kh = drev(8l+q), kw = drev(w0+w) — pre-baked into Hp
        const float4* hp = (const float4*)(Hp + (((size_t)(w0 + w)) << 9) + 8*l);
#pragma unroll
        for (int q = 0; q < 4; ++q) {
            float4 h2 = hp[q];
            v[2*q]   = cmul(v[2*q],   make_float2(h2.x, h2.y));
            v[2*q+1] = cmul(v[2*q+1], make_float2(h2.z, h2.w));
        }
    }
    fft512_inv(v, S, l);
    __syncthreads();                   // all waves done with scratch
#pragma unroll
    for (int k = 0; k < 8; ++k) smem[9*(l + 64*k) + w] = v[k];
    __syncthreads();
    {   // stage-out, float4 per lane, line-complete
        const int c = t & 3, u = t >> 2;
#pragma unroll
        for (int k = 0; k < 4; ++k) {
            int h = u + 128*k;
            float2 a = smem[9*h + 2*c], b = smem[9*h + 2*c + 1];
            *(float4*)(base + (size_t)h * 512 + 2*c) = make_float4(a.x, a.y, b.x, b.y);
        }
    }
}

// Pass 3: inverse FFT along W, scale 1/512^2; unpack Re -> plane 2m,
// Im -> plane 2m+1. TWO rows per wave, pipelined like pass 1.
__global__ __launch_bounds__(256) void pass3_rows(const float2* __restrict__ ws,
                                                  float* __restrict__ out) {
    __shared__ float2 smem[4 * 577];
    const int t = threadIdx.x;
    const int l = t & 63, w = t >> 6;
    float2* S = smem + w * 577;
    const size_t rp  = (size_t)blockIdx.x * 4 + w;   // row-pair 0..16383
    const size_t img = rp >> 8;                      // packed plane 0..63
    const size_t h0  = (rp & 255) * 2;
    const size_t grow = img * 512 + h0;
    const float4* srcA = (const float4*)(ws + grow * 512 + 8*l);
    const float4* srcB = (const float4*)(ws + (grow + 1) * 512 + 8*l);
    float2 va[8], vb[8];
#pragma unroll
    for (int q = 0; q < 4; ++q) {
        float4 p = srcA[q];
        va[2*q]   = make_float2(p.x, p.y);
        va[2*q+1] = make_float2(p.z, p.w);
    }
#pragma unroll
    for (int q = 0; q < 4; ++q) {
        float4 p = srcB[q];
        vb[2*q]   = make_float2(p.x, p.y);
        vb[2*q+1] = make_float2(p.z, p.w);
    }
    const float sc = 1.0f / (512.0f * 512.0f);
    float* dst1 = out + ((img * 2) << 18) + (h0 << 9);
    float* dst2 = dst1 + (1 << 18);
    fft512_inv(va, S, l);
#pragma unroll
    for (int k = 0; k < 8; ++k) {
        dst1[l + 64*k] = va[k].x * sc;
        dst2[l + 64*k] = va[k].y * sc;
    }
    fft512_inv(vb, S, l);
#pragma unroll
    for (int k = 0; k < 8; ++k) {
        dst1[512 + l + 64*k] = vb[k].x * sc;
        dst2[512 + l + 64*k] = vb[k].y * sc;
    }
}

extern "C" void kernel_launch(void* const* d_in, const int* in_sizes, int n_in,
                              void* d_out, int out_size, void* d_ws, size_t ws_size,
                              hipStream_t stream) {
    const float* x  = (const float*)d_in[0];   // [8,16,512,512]
    const float* Hr = (const float*)d_in[1];   // [512,512]
    const float* Hi = (const float*)d_in[2];   // [512,512]
    float* out = (float*)d_out;
    float2* ws = (float2*)d_ws;                // 128 MiB complex workspace (64 packed planes)
    float2* Hp = (float2*)d_out;               // 2 MiB of d_out reused as scratch;
                                               // pass 3 fully overwrites d_out after.

    pass1_rows<<<4608, 256, 0, stream>>>(x, ws, Hr, Hi, Hp);  // permH fused in
    pass2_cols<<<4096, 512, 0, stream>>>(ws, Hp);
    pass3_rows<<<4096, 256, 0, stream>>>(ws, out);
}